// Round 13
// baseline (1024.995 us; speedup 1.0000x reference)
//
#include <hip/hip_runtime.h>
#include <hip/hip_bf16.h>

#define BB 8
#define NN 1024
#define DD 128
#define HH 4
#define LL 4

typedef __attribute__((ext_vector_type(8))) _Float16 half8;
typedef __attribute__((ext_vector_type(2))) _Float16 h2v;
typedef __attribute__((ext_vector_type(4))) float f32x4;
typedef __attribute__((ext_vector_type(8))) unsigned short u16x8;

__device__ __forceinline__ unsigned short f2bf(float f) {
  union { float f; unsigned int u; } v; v.f = f;
  unsigned int u = v.u;
  return (unsigned short)((u + 0x7FFFu + ((u >> 16) & 1u)) >> 16);
}
__device__ __forceinline__ float bf2f(unsigned short s) {
  union { unsigned int u; float f; } v; v.u = ((unsigned int)s) << 16;
  return v.f;
}
__device__ __forceinline__ unsigned short f2h(float f) {
  union { _Float16 h; unsigned short u; } v; v.h = (_Float16)f;
  return v.u;
}
__device__ __forceinline__ float h2f(unsigned short u) {
  union { unsigned short u; _Float16 h; } v; v.u = u;
  return (float)v.h;
}
__device__ __forceinline__ half8 as_h8(uint4 u) {
  union { uint4 u; half8 h; } v; v.u = u; return v.h;
}

// ------- maskT bits: maskW[b][r][word w] bit t = (adj[b][p=32w+t][r] > 0) ------
__global__ __launch_bounds__(256) void k_maskT(const float* __restrict__ in,
                                               unsigned int* __restrict__ maskW) {
  __shared__ float t[32][33];
  int b = blockIdx.z;
  int x0 = blockIdx.x * 32, y0 = blockIdx.y * 32;
  int tx = threadIdx.x & 31, ty = threadIdx.x >> 5;
  const float* ib = in + (size_t)b * NN * NN;
#pragma unroll
  for (int j = 0; j < 32; j += 8)
    t[ty + j][tx] = ib[(size_t)(y0 + ty + j) * NN + x0 + tx];
  __syncthreads();
  const int half = (threadIdx.x >> 5) & 1;
#pragma unroll
  for (int j = 0; j < 32; j += 8) {
    bool nz = t[tx][ty + j] > 0.f;
    unsigned long long bl = __ballot(nz);
    unsigned int word = half ? (unsigned int)(bl >> 32) : (unsigned int)bl;
    if (tx == 0)
      maskW[((size_t)b * NN + x0 + ty + j) * 32 + (y0 >> 5)] = word;
  }
}

// --- compact adj rows: colidx/adjv/cidx10(byte-off) slots + cnt; zero-padded ---
__global__ __launch_bounds__(256) void k_build(const float* __restrict__ adj,
                                               unsigned short* __restrict__ colidx,
                                               unsigned short* __restrict__ adjv,
                                               unsigned int* __restrict__ cidx10,
                                               unsigned short* __restrict__ cnt) {
  const int b = blockIdx.y;
  const int wv = threadIdx.x >> 6, lane = threadIdx.x & 63;
  const int p = blockIdx.x * 4 + wv;
  const float* arow = adj + ((size_t)b * NN + p) * NN;
  const size_t base = ((size_t)b * NN + p) * 128;
  int run = 0;
  const unsigned long long lml = (lane == 63) ? 0x7FFFFFFFFFFFFFFFull
                                              : ((1ull << lane) - 1ull);
#pragma unroll
  for (int it = 0; it < 16; ++it) {
    float v = arow[it * 64 + lane];
    bool nz = v > 0.f;
    unsigned long long m = __ballot(nz);
    int pre = __popcll(m & lml);
    int slot = run + pre;
    if (nz && slot < 128) {
      colidx[base + slot] = (unsigned short)(it * 64 + lane);
      adjv[base + slot] = f2bf(v);
      cidx10[base + slot] = (unsigned int)(it * 64 + lane) << 10; // z-row byte off
    }
    run += __popcll(m);
  }
  const int nclamp = run > 128 ? 128 : run;
  for (int s2 = nclamp + lane; s2 < 128; s2 += 64) { // zero-pad tail slots
    colidx[base + s2] = 0;
    adjv[base + s2] = 0;
    cidx10[base + s2] = 0;
  }
  if (lane == 0) cnt[(size_t)b * NN + p] = (unsigned short)nclamp;
}

// ------- weight transpose: in [nm][128][Nn] fp32 -> out [nm][Nn][128] fp16 -----
__global__ __launch_bounds__(256) void k_wtrans(const float* __restrict__ in,
                                                unsigned short* __restrict__ out, int Nn) {
  __shared__ float t[32][33];
  int m = blockIdx.z;
  const float* ib = in + (size_t)m * 128 * Nn;
  unsigned short* ob = out + (size_t)m * Nn * 128;
  int k0 = blockIdx.x * 32, n0 = blockIdx.y * 32;
  int tx = threadIdx.x & 31, ty = threadIdx.x >> 5;
#pragma unroll
  for (int j = 0; j < 32; j += 8)
    t[ty + j][tx] = ib[(size_t)(k0 + ty + j) * Nn + n0 + tx];
  __syncthreads();
#pragma unroll
  for (int j = 0; j < 32; j += 8)
    ob[(size_t)(n0 + ty + j) * 128 + k0 + tx] = f2h(t[tx][ty + j]);
}

// ------- SIMT K=128 GEMM (embed only): C = A[M,128] @ Bw[128,Nn]; fp32+fp16 ----
__global__ __launch_bounds__(256) void k_gemm_k128(const float* __restrict__ A,
                                                   const float* __restrict__ Bw,
                                                   float* __restrict__ C,
                                                   unsigned short* __restrict__ Cbf,
                                                   int M, int Nn) {
  __shared__ __align__(16) float As[32][68];
  __shared__ __align__(16) float Bs[32][68];
  const int tm = blockIdx.x * 64, tn = blockIdx.y * 64;
  const int tid = threadIdx.x;
  const int ty = tid >> 4, tx = tid & 15;
  float acc[4][4] = {};
  for (int kc = 0; kc < 128; kc += 32) {
#pragma unroll
    for (int e = 0; e < 8; ++e) {
      int fl = tid + e * 256;
      int r = fl >> 5, k = fl & 31;
      As[k][r] = A[(size_t)(tm + r) * 128 + kc + k];
    }
#pragma unroll
    for (int e = 0; e < 8; ++e) {
      int fl = tid + e * 256;
      int k = fl >> 6, n = fl & 63;
      Bs[k][n] = Bw[(size_t)(kc + k) * Nn + tn + n];
    }
    __syncthreads();
#pragma unroll
    for (int kk = 0; kk < 32; ++kk) {
      float a4[4], b4[4];
      *(float4*)a4 = *(const float4*)&As[kk][ty * 4];
      *(float4*)b4 = *(const float4*)&Bs[kk][tx * 4];
#pragma unroll
      for (int i = 0; i < 4; ++i)
#pragma unroll
        for (int j = 0; j < 4; ++j) acc[i][j] += a4[i] * b4[j];
    }
    __syncthreads();
  }
#pragma unroll
  for (int i = 0; i < 4; ++i) {
    size_t base = (size_t)(tm + ty * 4 + i) * Nn + tn + tx * 4;
    *(float4*)&C[base] = *(float4*)acc[i];
    uint2 pv;
    pv.x = (unsigned int)f2h(acc[i][0]) | ((unsigned int)f2h(acc[i][1]) << 16);
    pv.y = (unsigned int)f2h(acc[i][2]) | ((unsigned int)f2h(acc[i][3]) << 16);
    *(uint2*)&Cbf[base] = pv;
  }
}

// ------- MFMA NT GEMM, K=128 (fp16): out[M,Nn] = A[M,128] @ Bt[Nn,128]^T -------
__global__ __launch_bounds__(256) void k_gemm_nt(const unsigned short* __restrict__ A,
                                                 const unsigned short* __restrict__ Bt,
                                                 const float* __restrict__ bias,
                                                 unsigned short* __restrict__ outp,
                                                 int Nn) {
  const int m0 = blockIdx.x * 64, n0 = blockIdx.y * 64;
  const int tid = threadIdx.x;
  const int wave = tid >> 6, lane = tid & 63;
  const int l15 = lane & 15, kq = lane >> 4;
  __shared__ __align__(16) unsigned short O[64][72];
  const unsigned short* aP = A + (size_t)(m0 + wave * 16 + l15) * 128;
  f32x4 acc[4] = {};
#pragma unroll
  for (int kk = 0; kk < 4; ++kk) {
    half8 aF = *(const half8*)(aP + (kk * 4 + kq) * 8);
#pragma unroll
    for (int cb = 0; cb < 4; ++cb) {
      half8 bF = *(const half8*)(Bt + (size_t)(n0 + cb * 16 + l15) * 128 + (kk * 4 + kq) * 8);
      acc[cb] = __builtin_amdgcn_mfma_f32_16x16x32_f16(aF, bF, acc[cb], 0, 0, 0);
    }
  }
#pragma unroll
  for (int cb = 0; cb < 4; ++cb) {
    float bv = bias ? bias[n0 + cb * 16 + l15] : 0.f;
#pragma unroll
    for (int rg = 0; rg < 4; ++rg)
      O[wave * 16 + kq * 4 + rg][cb * 16 + l15] = f2h(acc[cb][rg] + bv);
  }
  __syncthreads();
#pragma unroll
  for (int it = 0; it < 2; ++it) {
    int row = (tid >> 3) + it * 32, ch = tid & 7;
    *(uint4*)&outp[(size_t)(m0 + row) * Nn + n0 + ch * 8] = *(uint4*)&O[row][ch * 8];
  }
}

// ------- E tile via fp16 MFMA -> fp16 [p][r]: triangular grid (136 pairs) ------
__global__ __launch_bounds__(256) void k_e_st(const unsigned short* __restrict__ g,
                                              const unsigned short* __restrict__ h,
                                              unsigned short* __restrict__ e, int b0) {
  const int t0 = blockIdx.x; // 0..135 -> (tp <= tr)
  int tr = (int)((sqrtf(8.f * t0 + 1.f) - 1.f) * 0.5f);
  while ((tr + 1) * (tr + 2) / 2 <= t0) ++tr;
  while (tr * (tr + 1) / 2 > t0) --tr;
  const int tp = t0 - tr * (tr + 1) / 2;
  const int gi = blockIdx.y;
  const int b = b0 + (gi >> 2), i = gi & 3;
  const int p0 = tp * 64, r0 = tr * 64;
  const bool diag = (tp == tr);
  __shared__ __align__(16) char lds[32768];
  const int tid = threadIdx.x;
  const unsigned short* gb = g + (size_t)b * NN * 512 + i * 128;
  const unsigned short* hb = h + (size_t)b * NN * 512 + i * 128;
#pragma unroll
  for (int e2 = 0; e2 < 8; ++e2) {
    int fl = tid + e2 * 256;
    int t = fl >> 10, rem = fl & 1023;
    int row = rem >> 4, ch = rem & 15;
    const unsigned short* src = t ? hb : gb;
    uint4 v = *(const uint4*)(src + (size_t)(r0 + row) * 512 + ch * 8);
    *(uint4*)(lds + t * 16384 + row * 256 + ((ch ^ (row & 7)) * 16)) = v;
  }
  __syncthreads();
  const int wave = tid >> 6, lane = tid & 63;
  const int l15 = lane & 15, kq = lane >> 4;
  const unsigned short* aG = gb + (size_t)(p0 + wave * 16 + l15) * 512;
  const unsigned short* aH = hb + (size_t)(p0 + wave * 16 + l15) * 512;
  f32x4 acc[4] = {};
#pragma unroll
  for (int kk = 0; kk < 4; ++kk) {
    half8 gA = *(const half8*)(aG + (kk * 4 + kq) * 8);
    half8 hA = *(const half8*)(aH + (kk * 4 + kq) * 8);
#pragma unroll
    for (int cb = 0; cb < 4; ++cb) {
      int row = cb * 16 + l15;
      int chs = ((kk * 4 + kq) ^ (row & 7)) * 16;
      half8 gB = *(const half8*)(lds + row * 256 + chs);
      half8 hB = *(const half8*)(lds + 16384 + row * 256 + chs);
      acc[cb] = __builtin_amdgcn_mfma_f32_16x16x32_f16(gA, hB, acc[cb], 0, 0, 0);
      acc[cb] = __builtin_amdgcn_mfma_f32_16x16x32_f16(hA, gB, acc[cb], 0, 0, 0);
    }
  }
  __syncthreads();
  unsigned short* eN = (unsigned short*)lds;   // [64][72] fp16
  unsigned short* eT = eN + 64 * 72;
#pragma unroll
  for (int cb = 0; cb < 4; ++cb)
#pragma unroll
    for (int rg = 0; rg < 4; ++rg) {
      const int pl = wave * 16 + kq * 4 + rg, rl = cb * 16 + l15;
      const unsigned short v = f2h(acc[cb][rg]);
      eN[pl * 72 + rl] = v;
      if (!diag) eT[rl * 72 + pl] = v;
    }
  __syncthreads();
  unsigned short* eb = e + (size_t)gi * NN * NN;
#pragma unroll
  for (int it = 0; it < 2; ++it) {
    const int row = (tid >> 3) + it * 32, ch = tid & 7;
    *(uint4*)&eb[(size_t)(p0 + row) * NN + r0 + ch * 8] = *(uint4*)&eN[row * 72 + ch * 8];
    if (!diag)
      *(uint4*)&eb[(size_t)(r0 + row) * NN + p0 + ch * 8] = *(uint4*)&eT[row * 72 + ch * 8];
  }
}

// ------- both-branch stats, wave-per-row (no LDS/barriers): mx[r], inv[r] ------
__global__ __launch_bounds__(256) void k_stats3(const unsigned short* __restrict__ e,
                                                const unsigned int* __restrict__ m1,
                                                const unsigned int* __restrict__ m2,
                                                float2* __restrict__ stats,
                                                size_t statsS, int b0) {
  const int wid = threadIdx.x >> 6, lane = threadIdx.x & 63;
  const int col = blockIdx.x * 4 + wid; // local gi*N + r
  const int r = col & (NN - 1);
  const int gi = col >> 10;
  const int b = b0 + (gi >> 2);
  const unsigned short* erow = e + (size_t)col * NN + lane * 16;
  u16x8 ev0 = *(const u16x8*)erow;
  u16x8 ev1 = *(const u16x8*)(erow + 8);
  float evf[16];
#pragma unroll
  for (int j = 0; j < 8; ++j) {
    evf[j] = h2f((unsigned short)ev0[j]);
    evf[8 + j] = h2f((unsigned short)ev1[j]);
  }
  const size_t moff = ((size_t)b * NN + r) * 32 + (lane >> 1);
  const int sh = (lane & 1) * 16;
  unsigned int w1 = (m1[moff] >> sh) & 0xffffu;
  unsigned int w2 = (m2[moff] >> sh) & 0xffffu;
  float mx1 = 0.f, mx2 = 0.f; // masked entries contribute 0 -> max includes 0
#pragma unroll
  for (int j = 0; j < 16; ++j) {
    if ((w1 >> j) & 1u) mx1 = fmaxf(mx1, evf[j]);
    if ((w2 >> j) & 1u) mx2 = fmaxf(mx2, evf[j]);
  }
#pragma unroll
  for (int o = 32; o; o >>= 1) {
    mx1 = fmaxf(mx1, __shfl_xor(mx1, o));
    mx2 = fmaxf(mx2, __shfl_xor(mx2, o));
  }
  float ps1 = 0.f, ps2 = 0.f;
#pragma unroll
  for (int j = 0; j < 16; ++j) {
    float s1 = ((w1 >> j) & 1u) ? evf[j] : 0.f;
    float s2 = ((w2 >> j) & 1u) ? evf[j] : 0.f;
    ps1 += __expf(s1 - mx1);
    ps2 += __expf(s2 - mx2);
  }
#pragma unroll
  for (int o = 32; o; o >>= 1) {
    ps1 += __shfl_xor(ps1, o);
    ps2 += __shfl_xor(ps2, o);
  }
  if (lane == 0) {
    const size_t gcol = (((size_t)gi + (size_t)b0 * HH) << 10) + r;
    stats[gcol] = make_float2(mx1, 1.f / ps1);
    stats[statsS + gcol] = make_float2(mx2, 1.f / ps2);
  }
}

// ------- attw: att4[br][bl][p][head][128] word = f16(att) duplicated lo|hi ----
__global__ __launch_bounds__(256) void k_attw5(const unsigned short* __restrict__ e,
                                               const unsigned short* __restrict__ cidxB,
                                               const unsigned short* __restrict__ adjvB,
                                               const unsigned short* __restrict__ cntB,
                                               size_t adjS, size_t cntS,
                                               const float2* __restrict__ stats,
                                               size_t statsS,
                                               unsigned int* __restrict__ att4,
                                               size_t attS, int b0) {
  const int bl = blockIdx.x;            // batch on x -> XCD affinity
  const int br = blockIdx.z;
  const int head = blockIdx.y >> 8, ptile = blockIdx.y & 255;
  const int b = b0 + bl;
  const int gi = bl * HH + head;
  const unsigned short* cidx = cidxB + (size_t)br * adjS;
  const unsigned short* adjv = adjvB + (size_t)br * adjS;
  const int wv = threadIdx.x >> 6, lane = threadIdx.x & 63;
  const int p = ptile * 4 + wv;
  const int n = cntB[(size_t)br * cntS + (size_t)b * NN + p];
  const int np8 = (n + 7) & ~7;
  const size_t cbase = ((size_t)b * NN + p) * 128;
  const unsigned short* erow = e + ((size_t)gi * NN + p) * NN;
  const float2* st = stats + (size_t)br * statsS + (((size_t)gi + (size_t)b0 * HH) << 10);
  unsigned int* ob = att4 + (size_t)br * attS + (((size_t)bl * NN + p) * 4 + head) * 128;
  for (int s = lane; s < np8; s += 64) {
    unsigned int o = 0;
    if (s < n) {
      int r = cidx[cbase + s];
      float2 mi = st[r];
      float val = __expf(h2f(erow[r]) - mi.x) * mi.y * bf2f(adjv[cbase + s]);
      o = (unsigned int)f2h(val) * 0x10001u; // duplicated lo|hi
    }
    ob[s] = o;
  }
}

// ---- hWb[(b*N+n)*H+i] = sum_d h[...,d] * Wb_k[d] ------------------------------
__global__ __launch_bounds__(256) void k_hwb(const unsigned short* __restrict__ h,
                                             const float* __restrict__ Wbk,
                                             float* __restrict__ hWb) {
  const int wid = threadIdx.x >> 6, lane = threadIdx.x & 63;
  const int idx = blockIdx.x * 4 + wid;
  const unsigned short* hp = h + (size_t)idx * 128;
  float s = 0.f;
#pragma unroll
  for (int e = 0; e < 2; ++e) {
    int d = lane + e * 64;
    s += h2f(hp[d]) * Wbk[d];
  }
#pragma unroll
  for (int o = 32; o; o >>= 1) s += __shfl_xor(s, o);
  if (lane == 0) hWb[idx] = s;
}

// ---- sparse az: shared byte-offset list + dup-packed vals, pk_fma accumulate --
// MODE 0: az0 — beta in-kernel, mix -> z.  MODE 1: hop — read beta, mix -> z.
template <int MODE>
__global__ __launch_bounds__(256) void k_az10(const unsigned int* __restrict__ att4,
                                              size_t attS,
                                              const unsigned int* __restrict__ cidx10B,
                                              size_t adjS,
                                              const unsigned short* __restrict__ cntB,
                                              size_t cntS,
                                              const unsigned short* __restrict__ zin,
                                              size_t zinS,
                                              const unsigned short* __restrict__ h,
                                              const float* __restrict__ hWb,
                                              const float* __restrict__ Wbk,
                                              const float* __restrict__ bbk,
                                              float* __restrict__ betaB, size_t betaS,
                                              unsigned short* __restrict__ outB,
                                              size_t outS, int b0) {
  const int bl = blockIdx.x;  // batch on x -> XCD-local z/h working set
  const int br = blockIdx.z;
  const int b = b0 + bl;
  const int wv = threadIdx.x >> 6, lane = threadIdx.x & 63;
  const int p = blockIdx.y * 4 + wv;
  const int head = lane >> 4;
  const int n = cntB[(size_t)br * cntS + (size_t)b * NN + p];
  const int np8 = (n + 7) & ~7;
  const unsigned int* cof = cidx10B + (size_t)br * adjS + ((size_t)b * NN + p) * 128;
  const unsigned int* ap =
      att4 + (size_t)br * attS + (((size_t)bl * NN + p) * 4 + head) * 128;
  const char* zc = (const char*)(zin + (size_t)br * zinS + (size_t)b * NN * 512);
  const unsigned lb = (unsigned)lane * 16u; // byte offset within z row
  h2v acc4[4] = {};
  for (int s = 0; s < np8; s += 8) {
    uint4 c0 = *(const uint4*)(cof + s);     // 4 byte-offsets (bcast)
    uint4 c1 = *(const uint4*)(cof + s + 4);
    uint4 a0 = *(const uint4*)(ap + s);      // dup-packed vals (per head)
    uint4 a1 = *(const uint4*)(ap + s + 4);
    uint4 z0 = *(const uint4*)(zc + (c0.x + lb));
    uint4 z1 = *(const uint4*)(zc + (c0.y + lb));
    uint4 z2 = *(const uint4*)(zc + (c0.z + lb));
    uint4 z3 = *(const uint4*)(zc + (c0.w + lb));
    uint4 z4 = *(const uint4*)(zc + (c1.x + lb));
    uint4 z5 = *(const uint4*)(zc + (c1.y + lb));
    uint4 z6 = *(const uint4*)(zc + (c1.z + lb));
    uint4 z7 = *(const uint4*)(zc + (c1.w + lb));
#define ACCP(zq, aw)                                              \
    {                                                             \
      union { unsigned u; h2v h; } vv; vv.u = (aw);               \
      union { uint4 u; h2v h[4]; } zz; zz.u = zq;                 \
      acc4[0] += vv.h * zz.h[0];                                  \
      acc4[1] += vv.h * zz.h[1];                                  \
      acc4[2] += vv.h * zz.h[2];                                  \
      acc4[3] += vv.h * zz.h[3];                                  \
    }
    ACCP(z0, a0.x) ACCP(z1, a0.y) ACCP(z2, a0.z) ACCP(z3, a0.w)
    ACCP(z4, a1.x) ACCP(z5, a1.y) ACCP(z6, a1.z) ACCP(z7, a1.w)
#undef ACCP
  }
  float a[8];
#pragma unroll
  for (int j = 0; j < 4; ++j) {
    a[2 * j]     = fmaxf((float)acc4[j][0], 0.f);
    a[2 * j + 1] = fmaxf((float)acc4[j][1], 0.f);
  }
  const size_t gidx = ((size_t)b * NN + p) * HH + head;
  float bt;
  if (MODE == 0) {
    const float* wb2 = Wbk + 128 + (lane & 15) * 8;
    float part = 0.f;
#pragma unroll
    for (int j = 0; j < 8; ++j) part += a[j] * wb2[j];
    part += __shfl_xor(part, 1);
    part += __shfl_xor(part, 2);
    part += __shfl_xor(part, 4);
    part += __shfl_xor(part, 8); // full 128-dim sum within the 16-lane head group
    bt = 1.f / (1.f + __expf(-(hWb[gidx] + part + bbk[0])));
    if ((lane & 15) == 0) betaB[(size_t)br * betaS + gidx] = bt;
  } else {
    bt = betaB[(size_t)br * betaS + gidx];
  }
  const float om = 1.f - bt;
  const size_t obase = ((size_t)b * NN + p) * 512 + (size_t)lane * 8;
  half8 hf = as_h8(*(const uint4*)(h + obase));
  float zo[8];
#pragma unroll
  for (int j = 0; j < 8; ++j) zo[j] = bt * (float)hf[j] + om * a[j];
  uint4 zv;
  zv.x = (unsigned int)f2h(zo[0]) | ((unsigned int)f2h(zo[1]) << 16);
  zv.y = (unsigned int)f2h(zo[2]) | ((unsigned int)f2h(zo[3]) << 16);
  zv.z = (unsigned int)f2h(zo[4]) | ((unsigned int)f2h(zo[5]) << 16);
  zv.w = (unsigned int)f2h(zo[6]) | ((unsigned int)f2h(zo[7]) << 16);
  *(uint4*)(outB + (size_t)br * outS + obase) = zv;
}

// ---- out[n,d] = mean_i z2[n,i,d] - mean_i z1[n,i,d]; c fp32 + fp16 ------------
__global__ __launch_bounds__(256) void k_headmean2(const unsigned short* __restrict__ z1,
                                                   const unsigned short* __restrict__ z2,
                                                   float* __restrict__ outp,
                                                   unsigned short* __restrict__ outbf) {
  const int idx = blockIdx.x * 256 + threadIdx.x;
  const int d = idx & 127, bn = idx >> 7;
  const size_t base = (size_t)bn * 512 + d;
  float v1 = h2f(z1[base]) + h2f(z1[base + 128]) + h2f(z1[base + 256]) + h2f(z1[base + 384]);
  float v2 = h2f(z2[base]) + h2f(z2[base + 128]) + h2f(z2[base + 256]) + h2f(z2[base + 384]);
  float v = 0.25f * (v2 - v1);
  outp[idx] = v;
  outbf[idx] = f2h(v);
}

// ---------------- node mean (parallel) + MLP head ------------------------------
__global__ __launch_bounds__(1024) void k_final2(const float* __restrict__ c,
                                                 const float* __restrict__ valid,
                                                 const float* __restrict__ Wfc0,
                                                 const float* __restrict__ bfc0,
                                                 const float* __restrict__ Wfcm,
                                                 const float* __restrict__ bfcm,
                                                 const float* __restrict__ Wfcl,
                                                 const float* __restrict__ bfcl,
                                                 float* __restrict__ out) {
  const int b = blockIdx.x, tid = threadIdx.x;
  const int ns = tid >> 7, d = tid & 127;
  __shared__ float red[8][128];
  __shared__ float vsh[8];
  __shared__ float bufA[128], bufB[128];
  float s = 0.f, vs = 0.f;
  const float* cb = c + ((size_t)b * NN + ns * 128) * 128 + d;
  const float* vb = valid + (size_t)b * NN + ns * 128;
  for (int n2 = 0; n2 < 128; ++n2) {
    float vv = vb[n2];
    s += cb[(size_t)n2 * 128] * vv;
    vs += vv;
  }
  red[ns][d] = s;
  if (d == 0) vsh[ns] = vs;
  __syncthreads();
  if (tid < 128) {
    float m = 0.f, vt = 0.f;
#pragma unroll
    for (int j = 0; j < 8; ++j) { m += red[j][tid]; vt += vsh[j]; }
    bufA[tid] = m / vt;
  }
  __syncthreads();
  if (tid < 128) {
    float t = bfc0[tid];
    for (int m = 0; m < 128; ++m) t += bufA[m] * Wfc0[m * 128 + tid];
    bufB[tid] = fmaxf(t, 0.f);
  }
  __syncthreads();
  if (tid < 128) {
    float t = bfcm[tid];
    for (int m = 0; m < 128; ++m) t += bufB[m] * Wfcm[m * 128 + tid];
    bufA[tid] = fmaxf(t, 0.f);
  }
  __syncthreads();
  if (tid < 128) {
    float t = bfcm[128 + tid];
    for (int m = 0; m < 128; ++m) t += bufA[m] * Wfcm[128 * 128 + m * 128 + tid];
    bufB[tid] = fmaxf(t, 0.f);
  }
  __syncthreads();
  if (tid < 128) red[0][tid] = bufB[tid] * Wfcl[tid];
  __syncthreads();
  if (tid < 64) red[0][tid] += red[0][tid + 64];
  __syncthreads();
  if (tid == 0) {
    float r = 0.f;
#pragma unroll
    for (int j = 0; j < 64; ++j) r += red[0][j];
    out[b] = 1.f / (1.f + __expf(-(r + bfcl[0])));
  }
}

extern "C" void kernel_launch(void* const* d_in, const int* in_sizes, int n_in,
                              void* d_out, int out_size, void* d_ws, size_t ws_size,
                              hipStream_t stream) {
  (void)in_sizes; (void)n_in; (void)out_size;
  const float* x     = (const float*)d_in[0];
  const float* adj1  = (const float*)d_in[1];
  const float* adj2  = (const float*)d_in[2];
  const float* valid = (const float*)d_in[3];
  const float* Wemb  = (const float*)d_in[4];
  const float* Wh    = (const float*)d_in[5];
  const float* bh    = (const float*)d_in[6];
  const float* We    = (const float*)d_in[7];
  const float* Wb    = (const float*)d_in[8];
  const float* bb    = (const float*)d_in[9];
  const float* Wfc0  = (const float*)d_in[10];
  const float* bfc0  = (const float*)d_in[11];
  const float* Wfcm  = (const float*)d_in[12];
  const float* bfcm  = (const float*)d_in[13];
  const float* Wfcl  = (const float*)d_in[14];
  const float* bfcl  = (const float*)d_in[15];
  float* out = (float*)d_out;

  // branch strides (element counts)
  const size_t adjS  = (size_t)BB * NN * 128;     // u16 / u32 slot arrays
  const size_t cntS  = (size_t)BB * NN;           // u16
  const size_t betaS = (size_t)BB * NN * HH;      // f32
  const size_t zS    = (size_t)BB * NN * HH * DD; // f16
  const size_t statsS = (size_t)BB * HH * NN;     // float2

  // ---- workspace (fp32-element offsets) ----
  float* w = (float*)d_ws;
  size_t off = 0;
  float* c    = w + off; off += (size_t)BB * NN * DD;
  float* beta = w + off; off += 2 * betaS;
  float2* stats = (float2*)(w + off); off += 2 * statsS * 2;
  float* hWb  = w + off; off += (size_t)BB * NN * HH;
  unsigned short* c_bf = (unsigned short*)(w + off); off += (size_t)BB * NN * DD / 2;
  unsigned short* h_bf = (unsigned short*)(w + off); off += (size_t)BB * NN * HH * DD / 2;
  unsigned short* g_bf = (unsigned short*)(w + off); off += (size_t)BB * NN * HH * DD / 2;
  unsigned short* zP0  = (unsigned short*)(w + off); off += 2 * zS / 2;
  unsigned short* zP1  = (unsigned short*)(w + off); off += 2 * zS / 2;
  unsigned short* WhT  = (unsigned short*)(w + off); off += (size_t)LL * 512 * 128 / 2;
  unsigned short* WeT  = (unsigned short*)(w + off); off += (size_t)LL * 128 * 128 / 2;
  unsigned int* maskT1 = (unsigned int*)(w + off); off += (size_t)BB * NN * 32;
  unsigned int* maskT2 = (unsigned int*)(w + off); off += (size_t)BB * NN * 32;
  unsigned short* cidxB = (unsigned short*)(w + off); off += 2 * adjS / 2;
  unsigned short* adjvB = (unsigned short*)(w + off); off += 2 * adjS / 2;
  unsigned int* cidx10B = (unsigned int*)(w + off); off += 2 * adjS;
  unsigned short* cntB  = (unsigned short*)(w + off); off += (2 * cntS + 1) / 2;
  const size_t fixedF = off;
  const size_t eF = (size_t)HH * NN * NN / 2;  // per-batch fp16 E, floats
  const size_t aF = (size_t)NN * 512;          // per-batch per-branch att4, floats
  const size_t wsF = ws_size / sizeof(float);

  int G = 8;
  while (G > 1 && fixedF + (size_t)G * (eF + 2 * aF) > wsF) G >>= 1;

  unsigned short* e = (unsigned short*)(w + fixedF);
  unsigned int* att4 = (unsigned int*)(w + fixedF + (size_t)G * eF);
  const size_t attS = (size_t)G * NN * 512; // u32 branch stride [bl][p][head][128]

  k_maskT<<<dim3(32, 32, BB), 256, 0, stream>>>(adj1, maskT1);
  k_maskT<<<dim3(32, 32, BB), 256, 0, stream>>>(adj2, maskT2);
  k_build<<<dim3(256, BB), 256, 0, stream>>>(adj1, cidxB, adjvB, cidx10B, cntB);
  k_build<<<dim3(256, BB), 256, 0, stream>>>(adj2, cidxB + adjS, adjvB + adjS,
                                             cidx10B + adjS, cntB + cntS);
  k_wtrans<<<dim3(4, 16, LL), 256, 0, stream>>>(Wh, WhT, 512);
  k_wtrans<<<dim3(4, 4, LL), 256, 0, stream>>>(We, WeT, 128);
  k_gemm_k128<<<dim3(128, 2), 256, 0, stream>>>(x, Wemb, c, c_bf, BB * NN, DD);

  for (int k = 0; k < LL; ++k) {
    k_gemm_nt<<<dim3(128, 8), 256, 0, stream>>>(
        c_bf, WhT + (size_t)k * 512 * 128, bh + (size_t)k * 512, h_bf, 512);
    k_gemm_nt<<<dim3(512, 2), 256, 0, stream>>>(
        h_bf, WeT + (size_t)k * 128 * 128, nullptr, g_bf, 128);
    k_hwb<<<BB * NN * HH / 4, 256, 0, stream>>>(h_bf, Wb + (size_t)k * 2 * DD, hWb);
    for (int b0 = 0; b0 < BB; b0 += G) {
      k_e_st<<<dim3(136, G * HH), 256, 0, stream>>>(g_bf, h_bf, e, b0);
      k_stats3<<<G * HH * NN / 4, 256, 0, stream>>>(e, maskT1, maskT2, stats, statsS, b0);
      k_attw5<<<dim3(G, 1024, 2), 256, 0, stream>>>(
          e, cidxB, adjvB, cntB, adjS, cntS, stats, statsS, att4, attS, b0);
      // az0 fused (relu + beta + mix) for both branches -> zP0
      k_az10<0><<<dim3(G, 256, 2), 256, 0, stream>>>(
          att4, attS, cidx10B, adjS, cntB, cntS, h_bf, 0, h_bf, hWb,
          Wb + (size_t)k * 2 * DD, bb + k, beta, betaS, zP0, zS, b0);
      unsigned short *cur = zP0, *nxt = zP1;
      for (int t = 2; t <= k + 1; ++t) {
        k_az10<1><<<dim3(G, 256, 2), 256, 0, stream>>>(
            att4, attS, cidx10B, adjS, cntB, cntS, cur, zS, h_bf, nullptr, nullptr,
            nullptr, beta, betaS, nxt, zS, b0);
        unsigned short* tm = cur; cur = nxt; nxt = tm;
      }
      const size_t oH = (size_t)b0 * NN * 512;
      const size_t oC = (size_t)b0 * NN * DD;
      k_headmean2<<<G * 512, 256, 0, stream>>>(
          cur + oH, cur + zS + oH, c + oC, c_bf + oC);
    }
  }
  k_final2<<<BB, 1024, 0, stream>>>(c, valid, Wfc0, bfc0, Wfcm, bfcm, Wfcl, bfcl, out);
}

// Round 14
// 963.842 us; speedup vs baseline: 1.0634x; 1.0634x over previous
//
#include <hip/hip_runtime.h>
#include <hip/hip_bf16.h>

#define BB 8
#define NN 1024
#define DD 128
#define HH 4
#define LL 4

typedef __attribute__((ext_vector_type(8))) _Float16 half8;
typedef __attribute__((ext_vector_type(2))) _Float16 h2v;
typedef __attribute__((ext_vector_type(4))) float f32x4;
typedef __attribute__((ext_vector_type(8))) unsigned short u16x8;

__device__ __forceinline__ unsigned short f2bf(float f) {
  union { float f; unsigned int u; } v; v.f = f;
  unsigned int u = v.u;
  return (unsigned short)((u + 0x7FFFu + ((u >> 16) & 1u)) >> 16);
}
__device__ __forceinline__ float bf2f(unsigned short s) {
  union { unsigned int u; float f; } v; v.u = ((unsigned int)s) << 16;
  return v.f;
}
__device__ __forceinline__ unsigned short f2h(float f) {
  union { _Float16 h; unsigned short u; } v; v.h = (_Float16)f;
  return v.u;
}
__device__ __forceinline__ float h2f(unsigned short u) {
  union { unsigned short u; _Float16 h; } v; v.u = u;
  return (float)v.h;
}
__device__ __forceinline__ half8 as_h8(uint4 u) {
  union { uint4 u; half8 h; } v; v.u = u; return v.h;
}

// ------- maskT bits: maskW[b][r][word w] bit t = (adj[b][p=32w+t][r] > 0) ------
__global__ __launch_bounds__(256) void k_maskT(const float* __restrict__ in,
                                               unsigned int* __restrict__ maskW) {
  __shared__ float t[32][33];
  int b = blockIdx.z;
  int x0 = blockIdx.x * 32, y0 = blockIdx.y * 32;
  int tx = threadIdx.x & 31, ty = threadIdx.x >> 5;
  const float* ib = in + (size_t)b * NN * NN;
#pragma unroll
  for (int j = 0; j < 32; j += 8)
    t[ty + j][tx] = ib[(size_t)(y0 + ty + j) * NN + x0 + tx];
  __syncthreads();
  const int half = (threadIdx.x >> 5) & 1;
#pragma unroll
  for (int j = 0; j < 32; j += 8) {
    bool nz = t[tx][ty + j] > 0.f;
    unsigned long long bl = __ballot(nz);
    unsigned int word = half ? (unsigned int)(bl >> 32) : (unsigned int)bl;
    if (tx == 0)
      maskW[((size_t)b * NN + x0 + ty + j) * 32 + (y0 >> 5)] = word;
  }
}

// ------- compact adj rows: colidx/adjv slots (stride 128) + cnt; zero-padded ---
__global__ __launch_bounds__(256) void k_build(const float* __restrict__ adj,
                                               unsigned short* __restrict__ colidx,
                                               unsigned short* __restrict__ adjv,
                                               unsigned short* __restrict__ cnt) {
  const int b = blockIdx.y;
  const int wv = threadIdx.x >> 6, lane = threadIdx.x & 63;
  const int p = blockIdx.x * 4 + wv;
  const float* arow = adj + ((size_t)b * NN + p) * NN;
  const size_t base = ((size_t)b * NN + p) * 128;
  int run = 0;
  const unsigned long long lml = (lane == 63) ? 0x7FFFFFFFFFFFFFFFull
                                              : ((1ull << lane) - 1ull);
#pragma unroll
  for (int it = 0; it < 16; ++it) {
    float v = arow[it * 64 + lane];
    bool nz = v > 0.f;
    unsigned long long m = __ballot(nz);
    int pre = __popcll(m & lml);
    int slot = run + pre;
    if (nz && slot < 128) {
      colidx[base + slot] = (unsigned short)(it * 64 + lane);
      adjv[base + slot] = f2bf(v);
    }
    run += __popcll(m);
  }
  const int nclamp = run > 128 ? 128 : run;
  for (int s2 = nclamp + lane; s2 < 128; s2 += 64) { // zero-pad tail slots
    colidx[base + s2] = 0;
    adjv[base + s2] = 0;
  }
  if (lane == 0) cnt[(size_t)b * NN + p] = (unsigned short)nclamp;
}

// ------- weight transpose: in [nm][128][Nn] fp32 -> out [nm][Nn][128] fp16 -----
__global__ __launch_bounds__(256) void k_wtrans(const float* __restrict__ in,
                                                unsigned short* __restrict__ out, int Nn) {
  __shared__ float t[32][33];
  int m = blockIdx.z;
  const float* ib = in + (size_t)m * 128 * Nn;
  unsigned short* ob = out + (size_t)m * Nn * 128;
  int k0 = blockIdx.x * 32, n0 = blockIdx.y * 32;
  int tx = threadIdx.x & 31, ty = threadIdx.x >> 5;
#pragma unroll
  for (int j = 0; j < 32; j += 8)
    t[ty + j][tx] = ib[(size_t)(k0 + ty + j) * Nn + n0 + tx];
  __syncthreads();
#pragma unroll
  for (int j = 0; j < 32; j += 8)
    ob[(size_t)(n0 + ty + j) * 128 + k0 + tx] = f2h(t[tx][ty + j]);
}

// ------- SIMT K=128 GEMM (embed only): C = A[M,128] @ Bw[128,Nn]; fp32+fp16 ----
__global__ __launch_bounds__(256) void k_gemm_k128(const float* __restrict__ A,
                                                   const float* __restrict__ Bw,
                                                   float* __restrict__ C,
                                                   unsigned short* __restrict__ Cbf,
                                                   int M, int Nn) {
  __shared__ __align__(16) float As[32][68];
  __shared__ __align__(16) float Bs[32][68];
  const int tm = blockIdx.x * 64, tn = blockIdx.y * 64;
  const int tid = threadIdx.x;
  const int ty = tid >> 4, tx = tid & 15;
  float acc[4][4] = {};
  for (int kc = 0; kc < 128; kc += 32) {
#pragma unroll
    for (int e = 0; e < 8; ++e) {
      int fl = tid + e * 256;
      int r = fl >> 5, k = fl & 31;
      As[k][r] = A[(size_t)(tm + r) * 128 + kc + k];
    }
#pragma unroll
    for (int e = 0; e < 8; ++e) {
      int fl = tid + e * 256;
      int k = fl >> 6, n = fl & 63;
      Bs[k][n] = Bw[(size_t)(kc + k) * Nn + tn + n];
    }
    __syncthreads();
#pragma unroll
    for (int kk = 0; kk < 32; ++kk) {
      float a4[4], b4[4];
      *(float4*)a4 = *(const float4*)&As[kk][ty * 4];
      *(float4*)b4 = *(const float4*)&Bs[kk][tx * 4];
#pragma unroll
      for (int i = 0; i < 4; ++i)
#pragma unroll
        for (int j = 0; j < 4; ++j) acc[i][j] += a4[i] * b4[j];
    }
    __syncthreads();
  }
#pragma unroll
  for (int i = 0; i < 4; ++i) {
    size_t base = (size_t)(tm + ty * 4 + i) * Nn + tn + tx * 4;
    *(float4*)&C[base] = *(float4*)acc[i];
    uint2 pv;
    pv.x = (unsigned int)f2h(acc[i][0]) | ((unsigned int)f2h(acc[i][1]) << 16);
    pv.y = (unsigned int)f2h(acc[i][2]) | ((unsigned int)f2h(acc[i][3]) << 16);
    *(uint2*)&Cbf[base] = pv;
  }
}

// ------- MFMA NT GEMM, K=128 (fp16): out[M,Nn] = A[M,128] @ Bt[Nn,128]^T -------
__global__ __launch_bounds__(256) void k_gemm_nt(const unsigned short* __restrict__ A,
                                                 const unsigned short* __restrict__ Bt,
                                                 const float* __restrict__ bias,
                                                 unsigned short* __restrict__ outp,
                                                 int Nn) {
  const int m0 = blockIdx.x * 64, n0 = blockIdx.y * 64;
  const int tid = threadIdx.x;
  const int wave = tid >> 6, lane = tid & 63;
  const int l15 = lane & 15, kq = lane >> 4;
  __shared__ __align__(16) unsigned short O[64][72];
  const unsigned short* aP = A + (size_t)(m0 + wave * 16 + l15) * 128;
  f32x4 acc[4] = {};
#pragma unroll
  for (int kk = 0; kk < 4; ++kk) {
    half8 aF = *(const half8*)(aP + (kk * 4 + kq) * 8);
#pragma unroll
    for (int cb = 0; cb < 4; ++cb) {
      half8 bF = *(const half8*)(Bt + (size_t)(n0 + cb * 16 + l15) * 128 + (kk * 4 + kq) * 8);
      acc[cb] = __builtin_amdgcn_mfma_f32_16x16x32_f16(aF, bF, acc[cb], 0, 0, 0);
    }
  }
#pragma unroll
  for (int cb = 0; cb < 4; ++cb) {
    float bv = bias ? bias[n0 + cb * 16 + l15] : 0.f;
#pragma unroll
    for (int rg = 0; rg < 4; ++rg)
      O[wave * 16 + kq * 4 + rg][cb * 16 + l15] = f2h(acc[cb][rg] + bv);
  }
  __syncthreads();
#pragma unroll
  for (int it = 0; it < 2; ++it) {
    int row = (tid >> 3) + it * 32, ch = tid & 7;
    *(uint4*)&outp[(size_t)(m0 + row) * Nn + n0 + ch * 8] = *(uint4*)&O[row][ch * 8];
  }
}

// ------- E tile via fp16 MFMA -> fp16 [p][r]: triangular grid (136 pairs) ------
__global__ __launch_bounds__(256) void k_e_st(const unsigned short* __restrict__ g,
                                              const unsigned short* __restrict__ h,
                                              unsigned short* __restrict__ e, int b0) {
  const int t0 = blockIdx.x; // 0..135 -> (tp <= tr)
  int tr = (int)((sqrtf(8.f * t0 + 1.f) - 1.f) * 0.5f);
  while ((tr + 1) * (tr + 2) / 2 <= t0) ++tr;
  while (tr * (tr + 1) / 2 > t0) --tr;
  const int tp = t0 - tr * (tr + 1) / 2;
  const int gi = blockIdx.y;
  const int b = b0 + (gi >> 2), i = gi & 3;
  const int p0 = tp * 64, r0 = tr * 64;
  const bool diag = (tp == tr);
  __shared__ __align__(16) char lds[32768];
  const int tid = threadIdx.x;
  const unsigned short* gb = g + (size_t)b * NN * 512 + i * 128;
  const unsigned short* hb = h + (size_t)b * NN * 512 + i * 128;
#pragma unroll
  for (int e2 = 0; e2 < 8; ++e2) {
    int fl = tid + e2 * 256;
    int t = fl >> 10, rem = fl & 1023;
    int row = rem >> 4, ch = rem & 15;
    const unsigned short* src = t ? hb : gb;
    uint4 v = *(const uint4*)(src + (size_t)(r0 + row) * 512 + ch * 8);
    *(uint4*)(lds + t * 16384 + row * 256 + ((ch ^ (row & 7)) * 16)) = v;
  }
  __syncthreads();
  const int wave = tid >> 6, lane = tid & 63;
  const int l15 = lane & 15, kq = lane >> 4;
  const unsigned short* aG = gb + (size_t)(p0 + wave * 16 + l15) * 512;
  const unsigned short* aH = hb + (size_t)(p0 + wave * 16 + l15) * 512;
  f32x4 acc[4] = {};
#pragma unroll
  for (int kk = 0; kk < 4; ++kk) {
    half8 gA = *(const half8*)(aG + (kk * 4 + kq) * 8);
    half8 hA = *(const half8*)(aH + (kk * 4 + kq) * 8);
#pragma unroll
    for (int cb = 0; cb < 4; ++cb) {
      int row = cb * 16 + l15;
      int chs = ((kk * 4 + kq) ^ (row & 7)) * 16;
      half8 gB = *(const half8*)(lds + row * 256 + chs);
      half8 hB = *(const half8*)(lds + 16384 + row * 256 + chs);
      acc[cb] = __builtin_amdgcn_mfma_f32_16x16x32_f16(gA, hB, acc[cb], 0, 0, 0);
      acc[cb] = __builtin_amdgcn_mfma_f32_16x16x32_f16(hA, gB, acc[cb], 0, 0, 0);
    }
  }
  __syncthreads();
  unsigned short* eN = (unsigned short*)lds;   // [64][72] fp16
  unsigned short* eT = eN + 64 * 72;
#pragma unroll
  for (int cb = 0; cb < 4; ++cb)
#pragma unroll
    for (int rg = 0; rg < 4; ++rg) {
      const int pl = wave * 16 + kq * 4 + rg, rl = cb * 16 + l15;
      const unsigned short v = f2h(acc[cb][rg]);
      eN[pl * 72 + rl] = v;
      if (!diag) eT[rl * 72 + pl] = v;
    }
  __syncthreads();
  unsigned short* eb = e + (size_t)gi * NN * NN;
#pragma unroll
  for (int it = 0; it < 2; ++it) {
    const int row = (tid >> 3) + it * 32, ch = tid & 7;
    *(uint4*)&eb[(size_t)(p0 + row) * NN + r0 + ch * 8] = *(uint4*)&eN[row * 72 + ch * 8];
    if (!diag)
      *(uint4*)&eb[(size_t)(r0 + row) * NN + p0 + ch * 8] = *(uint4*)&eT[row * 72 + ch * 8];
  }
}

// ------- both-branch stats, wave-per-row (no LDS/barriers): mx[r], inv[r] ------
__global__ __launch_bounds__(256) void k_stats3(const unsigned short* __restrict__ e,
                                                const unsigned int* __restrict__ m1,
                                                const unsigned int* __restrict__ m2,
                                                float2* __restrict__ stats,
                                                size_t statsS, int b0) {
  const int wid = threadIdx.x >> 6, lane = threadIdx.x & 63;
  const int col = blockIdx.x * 4 + wid; // local gi*N + r
  const int r = col & (NN - 1);
  const int gi = col >> 10;
  const int b = b0 + (gi >> 2);
  const unsigned short* erow = e + (size_t)col * NN + lane * 16;
  u16x8 ev0 = *(const u16x8*)erow;
  u16x8 ev1 = *(const u16x8*)(erow + 8);
  float evf[16];
#pragma unroll
  for (int j = 0; j < 8; ++j) {
    evf[j] = h2f((unsigned short)ev0[j]);
    evf[8 + j] = h2f((unsigned short)ev1[j]);
  }
  const size_t moff = ((size_t)b * NN + r) * 32 + (lane >> 1);
  const int sh = (lane & 1) * 16;
  unsigned int w1 = (m1[moff] >> sh) & 0xffffu;
  unsigned int w2 = (m2[moff] >> sh) & 0xffffu;
  float mx1 = 0.f, mx2 = 0.f; // masked entries contribute 0 -> max includes 0
#pragma unroll
  for (int j = 0; j < 16; ++j) {
    if ((w1 >> j) & 1u) mx1 = fmaxf(mx1, evf[j]);
    if ((w2 >> j) & 1u) mx2 = fmaxf(mx2, evf[j]);
  }
#pragma unroll
  for (int o = 32; o; o >>= 1) {
    mx1 = fmaxf(mx1, __shfl_xor(mx1, o));
    mx2 = fmaxf(mx2, __shfl_xor(mx2, o));
  }
  float ps1 = 0.f, ps2 = 0.f;
#pragma unroll
  for (int j = 0; j < 16; ++j) {
    float s1 = ((w1 >> j) & 1u) ? evf[j] : 0.f;
    float s2 = ((w2 >> j) & 1u) ? evf[j] : 0.f;
    ps1 += __expf(s1 - mx1);
    ps2 += __expf(s2 - mx2);
  }
#pragma unroll
  for (int o = 32; o; o >>= 1) {
    ps1 += __shfl_xor(ps1, o);
    ps2 += __shfl_xor(ps2, o);
  }
  if (lane == 0) {
    const size_t gcol = (((size_t)gi + (size_t)b0 * HH) << 10) + r;
    stats[gcol] = make_float2(mx1, 1.f / ps1);
    stats[statsS + gcol] = make_float2(mx2, 1.f / ps2);
  }
}

// ------- attw: att4[br][bl][p][head][128] word = (r<<16)|f16(att); pad np8 -----
__global__ __launch_bounds__(256) void k_attw4(const unsigned short* __restrict__ e,
                                               const unsigned short* __restrict__ cidxB,
                                               const unsigned short* __restrict__ adjvB,
                                               const unsigned short* __restrict__ cntB,
                                               size_t adjS, size_t cntS,
                                               const float2* __restrict__ stats,
                                               size_t statsS,
                                               unsigned int* __restrict__ att4,
                                               size_t attS, int b0) {
  const int bl = blockIdx.x;            // batch on x -> XCD affinity
  const int br = blockIdx.z;
  const int head = blockIdx.y >> 8, ptile = blockIdx.y & 255;
  const int b = b0 + bl;
  const int gi = bl * HH + head;
  const unsigned short* cidx = cidxB + (size_t)br * adjS;
  const unsigned short* adjv = adjvB + (size_t)br * adjS;
  const int wv = threadIdx.x >> 6, lane = threadIdx.x & 63;
  const int p = ptile * 4 + wv;
  const int n = cntB[(size_t)br * cntS + (size_t)b * NN + p];
  const int np8 = (n + 7) & ~7;
  const size_t cbase = ((size_t)b * NN + p) * 128;
  const unsigned short* erow = e + ((size_t)gi * NN + p) * NN;
  const float2* st = stats + (size_t)br * statsS + (((size_t)gi + (size_t)b0 * HH) << 10);
  unsigned int* ob = att4 + (size_t)br * attS + (((size_t)bl * NN + p) * 4 + head) * 128;
  for (int s = lane; s < np8; s += 64) {
    unsigned int o = 0;
    if (s < n) {
      int r = cidx[cbase + s];
      float2 mi = st[r];
      float val = __expf(h2f(erow[r]) - mi.x) * mi.y * bf2f(adjv[cbase + s]);
      o = ((unsigned int)r << 16) | (unsigned int)f2h(val);
    }
    ob[s] = o;
  }
}

// ---- hWb[(b*N+n)*H+i] = sum_d h[...,d] * Wb_k[d] ------------------------------
__global__ __launch_bounds__(256) void k_hwb(const unsigned short* __restrict__ h,
                                             const float* __restrict__ Wbk,
                                             float* __restrict__ hWb) {
  const int wid = threadIdx.x >> 6, lane = threadIdx.x & 63;
  const int idx = blockIdx.x * 4 + wid;
  const unsigned short* hp = h + (size_t)idx * 128;
  float s = 0.f;
#pragma unroll
  for (int e = 0; e < 2; ++e) {
    int d = lane + e * 64;
    s += h2f(hp[d]) * Wbk[d];
  }
#pragma unroll
  for (int o = 32; o; o >>= 1) s += __shfl_xor(s, o);
  if (lane == 0) hWb[idx] = s;
}

// ---- sparse az, 4 heads/wave, pk_fma accumulate, 8-slot unroll + att prefetch -
// MODE 0: az0 — beta in-kernel, mix -> z.  MODE 1: hop — read beta, mix -> z.
template <int MODE>
__global__ __launch_bounds__(256) void k_az9(const unsigned int* __restrict__ att4,
                                             size_t attS,
                                             const unsigned short* __restrict__ cntB,
                                             size_t cntS,
                                             const unsigned short* __restrict__ zin,
                                             size_t zinS,
                                             const unsigned short* __restrict__ h,
                                             const float* __restrict__ hWb,
                                             const float* __restrict__ Wbk,
                                             const float* __restrict__ bbk,
                                             float* __restrict__ betaB, size_t betaS,
                                             unsigned short* __restrict__ outB,
                                             size_t outS, int b0) {
  const int bl = blockIdx.x;  // batch on x -> XCD-local z/h working set
  const int br = blockIdx.z;
  const int b = b0 + bl;
  const int wv = threadIdx.x >> 6, lane = threadIdx.x & 63;
  const int p = blockIdx.y * 4 + wv;
  const int head = lane >> 4;
  const int n = cntB[(size_t)br * cntS + (size_t)b * NN + p];
  const int np8 = (n + 7) & ~7;
  const unsigned int* ap =
      att4 + (size_t)br * attS + (((size_t)bl * NN + p) * 4 + head) * 128;
  const unsigned short* zbase = zin + (size_t)br * zinS + (size_t)b * NN * 512;
  const unsigned laneoff = (unsigned)lane * 8u;
  h2v acc4[4] = {};
  uint4 awA, awB, nwA, nwB;
  if (np8 > 0) {
    awA = *(const uint4*)(ap);
    awB = *(const uint4*)(ap + 4);
  }
  for (int s = 0; s < np8; s += 8) {
    if (s + 8 < np8) { // prefetch next iteration's att words
      nwA = *(const uint4*)(ap + s + 8);
      nwB = *(const uint4*)(ap + s + 12);
    }
    uint4 z0 = *(const uint4*)(zbase + (((awA.x >> 7) & 0xFFFFFE00u) + laneoff));
    uint4 z1 = *(const uint4*)(zbase + (((awA.y >> 7) & 0xFFFFFE00u) + laneoff));
    uint4 z2 = *(const uint4*)(zbase + (((awA.z >> 7) & 0xFFFFFE00u) + laneoff));
    uint4 z3 = *(const uint4*)(zbase + (((awA.w >> 7) & 0xFFFFFE00u) + laneoff));
    uint4 z4 = *(const uint4*)(zbase + (((awB.x >> 7) & 0xFFFFFE00u) + laneoff));
    uint4 z5 = *(const uint4*)(zbase + (((awB.y >> 7) & 0xFFFFFE00u) + laneoff));
    uint4 z6 = *(const uint4*)(zbase + (((awB.z >> 7) & 0xFFFFFE00u) + laneoff));
    uint4 z7 = *(const uint4*)(zbase + (((awB.w >> 7) & 0xFFFFFE00u) + laneoff));
#define ACCP(zq, aw)                                              \
    {                                                             \
      unsigned lo = (aw) & 0xffffu;                               \
      union { unsigned u; h2v h; } vv; vv.u = lo | (lo << 16);    \
      union { uint4 u; h2v h[4]; } zz; zz.u = zq;                 \
      acc4[0] += vv.h * zz.h[0];                                  \
      acc4[1] += vv.h * zz.h[1];                                  \
      acc4[2] += vv.h * zz.h[2];                                  \
      acc4[3] += vv.h * zz.h[3];                                  \
    }
    ACCP(z0, awA.x) ACCP(z1, awA.y) ACCP(z2, awA.z) ACCP(z3, awA.w)
    ACCP(z4, awB.x) ACCP(z5, awB.y) ACCP(z6, awB.z) ACCP(z7, awB.w)
#undef ACCP
    awA = nwA; awB = nwB;
  }
  float a[8];
#pragma unroll
  for (int j = 0; j < 4; ++j) {
    a[2 * j]     = fmaxf((float)acc4[j][0], 0.f);
    a[2 * j + 1] = fmaxf((float)acc4[j][1], 0.f);
  }
  const size_t gidx = ((size_t)b * NN + p) * HH + head;
  float bt;
  if (MODE == 0) {
    const float* wb2 = Wbk + 128 + (lane & 15) * 8;
    float part = 0.f;
#pragma unroll
    for (int j = 0; j < 8; ++j) part += a[j] * wb2[j];
    part += __shfl_xor(part, 1);
    part += __shfl_xor(part, 2);
    part += __shfl_xor(part, 4);
    part += __shfl_xor(part, 8); // full 128-dim sum within the 16-lane head group
    bt = 1.f / (1.f + __expf(-(hWb[gidx] + part + bbk[0])));
    if ((lane & 15) == 0) betaB[(size_t)br * betaS + gidx] = bt;
  } else {
    bt = betaB[(size_t)br * betaS + gidx];
  }
  const float om = 1.f - bt;
  const size_t obase = ((size_t)b * NN + p) * 512 + laneoff;
  half8 hf = as_h8(*(const uint4*)(h + obase));
  float zo[8];
#pragma unroll
  for (int j = 0; j < 8; ++j) zo[j] = bt * (float)hf[j] + om * a[j];
  uint4 zv;
  zv.x = (unsigned int)f2h(zo[0]) | ((unsigned int)f2h(zo[1]) << 16);
  zv.y = (unsigned int)f2h(zo[2]) | ((unsigned int)f2h(zo[3]) << 16);
  zv.z = (unsigned int)f2h(zo[4]) | ((unsigned int)f2h(zo[5]) << 16);
  zv.w = (unsigned int)f2h(zo[6]) | ((unsigned int)f2h(zo[7]) << 16);
  *(uint4*)(outB + (size_t)br * outS + obase) = zv;
}

// ---- out[n,d] = mean_i z2[n,i,d] - mean_i z1[n,i,d]; c fp32 + fp16 ------------
__global__ __launch_bounds__(256) void k_headmean2(const unsigned short* __restrict__ z1,
                                                   const unsigned short* __restrict__ z2,
                                                   float* __restrict__ outp,
                                                   unsigned short* __restrict__ outbf) {
  const int idx = blockIdx.x * 256 + threadIdx.x;
  const int d = idx & 127, bn = idx >> 7;
  const size_t base = (size_t)bn * 512 + d;
  float v1 = h2f(z1[base]) + h2f(z1[base + 128]) + h2f(z1[base + 256]) + h2f(z1[base + 384]);
  float v2 = h2f(z2[base]) + h2f(z2[base + 128]) + h2f(z2[base + 256]) + h2f(z2[base + 384]);
  float v = 0.25f * (v2 - v1);
  outp[idx] = v;
  outbf[idx] = f2h(v);
}

// ---------------- node mean (parallel) + MLP head ------------------------------
__global__ __launch_bounds__(1024) void k_final2(const float* __restrict__ c,
                                                 const float* __restrict__ valid,
                                                 const float* __restrict__ Wfc0,
                                                 const float* __restrict__ bfc0,
                                                 const float* __restrict__ Wfcm,
                                                 const float* __restrict__ bfcm,
                                                 const float* __restrict__ Wfcl,
                                                 const float* __restrict__ bfcl,
                                                 float* __restrict__ out) {
  const int b = blockIdx.x, tid = threadIdx.x;
  const int ns = tid >> 7, d = tid & 127;
  __shared__ float red[8][128];
  __shared__ float vsh[8];
  __shared__ float bufA[128], bufB[128];
  float s = 0.f, vs = 0.f;
  const float* cb = c + ((size_t)b * NN + ns * 128) * 128 + d;
  const float* vb = valid + (size_t)b * NN + ns * 128;
  for (int n2 = 0; n2 < 128; ++n2) {
    float vv = vb[n2];
    s += cb[(size_t)n2 * 128] * vv;
    vs += vv;
  }
  red[ns][d] = s;
  if (d == 0) vsh[ns] = vs;
  __syncthreads();
  if (tid < 128) {
    float m = 0.f, vt = 0.f;
#pragma unroll
    for (int j = 0; j < 8; ++j) { m += red[j][tid]; vt += vsh[j]; }
    bufA[tid] = m / vt;
  }
  __syncthreads();
  if (tid < 128) {
    float t = bfc0[tid];
    for (int m = 0; m < 128; ++m) t += bufA[m] * Wfc0[m * 128 + tid];
    bufB[tid] = fmaxf(t, 0.f);
  }
  __syncthreads();
  if (tid < 128) {
    float t = bfcm[tid];
    for (int m = 0; m < 128; ++m) t += bufB[m] * Wfcm[m * 128 + tid];
    bufA[tid] = fmaxf(t, 0.f);
  }
  __syncthreads();
  if (tid < 128) {
    float t = bfcm[128 + tid];
    for (int m = 0; m < 128; ++m) t += bufA[m] * Wfcm[128 * 128 + m * 128 + tid];
    bufB[tid] = fmaxf(t, 0.f);
  }
  __syncthreads();
  if (tid < 128) red[0][tid] = bufB[tid] * Wfcl[tid];
  __syncthreads();
  if (tid < 64) red[0][tid] += red[0][tid + 64];
  __syncthreads();
  if (tid == 0) {
    float r = 0.f;
#pragma unroll
    for (int j = 0; j < 64; ++j) r += red[0][j];
    out[b] = 1.f / (1.f + __expf(-(r + bfcl[0])));
  }
}

extern "C" void kernel_launch(void* const* d_in, const int* in_sizes, int n_in,
                              void* d_out, int out_size, void* d_ws, size_t ws_size,
                              hipStream_t stream) {
  (void)in_sizes; (void)n_in; (void)out_size;
  const float* x     = (const float*)d_in[0];
  const float* adj1  = (const float*)d_in[1];
  const float* adj2  = (const float*)d_in[2];
  const float* valid = (const float*)d_in[3];
  const float* Wemb  = (const float*)d_in[4];
  const float* Wh    = (const float*)d_in[5];
  const float* bh    = (const float*)d_in[6];
  const float* We    = (const float*)d_in[7];
  const float* Wb    = (const float*)d_in[8];
  const float* bb    = (const float*)d_in[9];
  const float* Wfc0  = (const float*)d_in[10];
  const float* bfc0  = (const float*)d_in[11];
  const float* Wfcm  = (const float*)d_in[12];
  const float* bfcm  = (const float*)d_in[13];
  const float* Wfcl  = (const float*)d_in[14];
  const float* bfcl  = (const float*)d_in[15];
  float* out = (float*)d_out;

  // branch strides (element counts)
  const size_t adjS  = (size_t)BB * NN * 128;     // u16
  const size_t cntS  = (size_t)BB * NN;           // u16
  const size_t betaS = (size_t)BB * NN * HH;      // f32
  const size_t zS    = (size_t)BB * NN * HH * DD; // f16
  const size_t statsS = (size_t)BB * HH * NN;     // float2

  // ---- workspace (fp32-element offsets) ----
  float* w = (float*)d_ws;
  size_t off = 0;
  float* c    = w + off; off += (size_t)BB * NN * DD;
  float* beta = w + off; off += 2 * betaS;
  float2* stats = (float2*)(w + off); off += 2 * statsS * 2;
  float* hWb  = w + off; off += (size_t)BB * NN * HH;
  unsigned short* c_bf = (unsigned short*)(w + off); off += (size_t)BB * NN * DD / 2;
  unsigned short* h_bf = (unsigned short*)(w + off); off += (size_t)BB * NN * HH * DD / 2;
  unsigned short* g_bf = (unsigned short*)(w + off); off += (size_t)BB * NN * HH * DD / 2;
  unsigned short* zP0  = (unsigned short*)(w + off); off += 2 * zS / 2;
  unsigned short* zP1  = (unsigned short*)(w + off); off += 2 * zS / 2;
  unsigned short* WhT  = (unsigned short*)(w + off); off += (size_t)LL * 512 * 128 / 2;
  unsigned short* WeT  = (unsigned short*)(w + off); off += (size_t)LL * 128 * 128 / 2;
  unsigned int* maskT1 = (unsigned int*)(w + off); off += (size_t)BB * NN * 32;
  unsigned int* maskT2 = (unsigned int*)(w + off); off += (size_t)BB * NN * 32;
  unsigned short* cidxB = (unsigned short*)(w + off); off += 2 * adjS / 2;
  unsigned short* adjvB = (unsigned short*)(w + off); off += 2 * adjS / 2;
  unsigned short* cntB  = (unsigned short*)(w + off); off += (2 * cntS + 1) / 2;
  const size_t fixedF = off;
  const size_t eF = (size_t)HH * NN * NN / 2;  // per-batch fp16 E, floats
  const size_t aF = (size_t)NN * 512;          // per-batch per-branch att4, floats
  const size_t wsF = ws_size / sizeof(float);

  int G = 8;
  while (G > 1 && fixedF + (size_t)G * (eF + 2 * aF) > wsF) G >>= 1;

  unsigned short* e = (unsigned short*)(w + fixedF);
  unsigned int* att4 = (unsigned int*)(w + fixedF + (size_t)G * eF);
  const size_t attS = (size_t)G * NN * 512; // u32 branch stride [bl][p][head][128]

  k_maskT<<<dim3(32, 32, BB), 256, 0, stream>>>(adj1, maskT1);
  k_maskT<<<dim3(32, 32, BB), 256, 0, stream>>>(adj2, maskT2);
  k_build<<<dim3(256, BB), 256, 0, stream>>>(adj1, cidxB, adjvB, cntB);
  k_build<<<dim3(256, BB), 256, 0, stream>>>(adj2, cidxB + adjS, adjvB + adjS, cntB + cntS);
  k_wtrans<<<dim3(4, 16, LL), 256, 0, stream>>>(Wh, WhT, 512);
  k_wtrans<<<dim3(4, 4, LL), 256, 0, stream>>>(We, WeT, 128);
  k_gemm_k128<<<dim3(128, 2), 256, 0, stream>>>(x, Wemb, c, c_bf, BB * NN, DD);

  for (int k = 0; k < LL; ++k) {
    k_gemm_nt<<<dim3(128, 8), 256, 0, stream>>>(
        c_bf, WhT + (size_t)k * 512 * 128, bh + (size_t)k * 512, h_bf, 512);
    k_gemm_nt<<<dim3(512, 2), 256, 0, stream>>>(
        h_bf, WeT + (size_t)k * 128 * 128, nullptr, g_bf, 128);
    k_hwb<<<BB * NN * HH / 4, 256, 0, stream>>>(h_bf, Wb + (size_t)k * 2 * DD, hWb);
    for (int b0 = 0; b0 < BB; b0 += G) {
      k_e_st<<<dim3(136, G * HH), 256, 0, stream>>>(g_bf, h_bf, e, b0);
      k_stats3<<<G * HH * NN / 4, 256, 0, stream>>>(e, maskT1, maskT2, stats, statsS, b0);
      k_attw4<<<dim3(G, 1024, 2), 256, 0, stream>>>(
          e, cidxB, adjvB, cntB, adjS, cntS, stats, statsS, att4, attS, b0);
      // az0 fused (relu + beta + mix) for both branches -> zP0
      k_az9<0><<<dim3(G, 256, 2), 256, 0, stream>>>(
          att4, attS, cntB, cntS, h_bf, 0, h_bf, hWb,
          Wb + (size_t)k * 2 * DD, bb + k, beta, betaS, zP0, zS, b0);
      unsigned short *cur = zP0, *nxt = zP1;
      for (int t = 2; t <= k + 1; ++t) {
        k_az9<1><<<dim3(G, 256, 2), 256, 0, stream>>>(
            att4, attS, cntB, cntS, cur, zS, h_bf, nullptr, nullptr, nullptr,
            beta, betaS, nxt, zS, b0);
        unsigned short* tm = cur; cur = nxt; nxt = tm;
      }
      const size_t oH = (size_t)b0 * NN * 512;
      const size_t oC = (size_t)b0 * NN * DD;
      k_headmean2<<<G * 512, 256, 0, stream>>>(
          cur + oH, cur + zS + oH, c + oC, c_bf + oC);
    }
  }
  k_final2<<<BB, 1024, 0, stream>>>(c, valid, Wfc0, bfc0, Wfcm, bfcm, Wfcl, bfcl, out);
}